// Round 1
// baseline (183.423 us; speedup 1.0000x reference)
//
#include <hip/hip_runtime.h>

constexpr int S_LEN = 2048;
constexpr int HEADS = 16;
constexpr int DDIM  = 64;      // head dim
constexpr int QT    = 64;      // queries per block
constexpr float SCALE = 0.125f;   // 64^-0.5
constexpr float NEG   = -1e30f;

// LDS rows of 64 floats (256B), XOR-swizzled within the row so that
// 16 consecutive rows read at the same column hit 16 distinct 16B slots.
// float-index version of: byte_in_row = d*4 ^ ((row&15)<<4)
__device__ __forceinline__ int swz(int row, int d0) {
    return row * 64 + (d0 ^ ((row & 15) << 2));
}

__launch_bounds__(256, 2)
__global__ void fattn_kernel(const float* __restrict__ Q, const float* __restrict__ K,
                             const float* __restrict__ V, float* __restrict__ O) {
    __shared__ __align__(16) float q_s[QT * 64];
    __shared__ __align__(16) float k_s[64 * 64];
    __shared__ __align__(16) float v_s[64 * 64];
    __shared__ __align__(16) float p_s[4][64 * 16];   // per-wave P^T: [key j][query i_local]

    const int tid  = threadIdx.x;
    const int wave = tid >> 6;
    const int lane = tid & 63;

    const int ntile = S_LEN / QT;                 // 32
    const int qt = blockIdx.x % ntile;
    const int bh = blockIdx.x / ntile;
    const int b  = bh / HEADS, h = bh % HEADS;
    const int q0 = qt * QT;

    const float* Qbase = Q + ((long)b * S_LEN * HEADS + h) * DDIM;  // + s*1024 + d
    const float* Kbase = K + ((long)b * S_LEN * HEADS + h) * DDIM;
    const float* Vbase = V + ((long)b * S_LEN * HEADS + h) * DDIM;
    float*       Obase = O + ((long)b * S_LEN * HEADS + h) * DDIM;

    // ---- staging helpers -------------------------------------------------
    // RoPE rows: 512 tasks = 64 rows x 8 col-groups; each task handles
    // d0..d0+3 and d0+32..d0+35 (the rotate_half partner pair).
    auto stage_rope = [&](const float* base, int row0, float* dst) {
        #pragma unroll
        for (int r = 0; r < 2; ++r) {
            int task = tid + r * 256;
            int row  = task >> 3;
            int d0   = (task & 7) * 4;
            int sidx = row0 + row;
            const float* src = base + (long)sidx * (HEADS * DDIM) + d0;
            float4 lo = *reinterpret_cast<const float4*>(src);
            float4 hi = *reinterpret_cast<const float4*>(src + 32);
            float olo[4], ohi[4];
            const float* lop = reinterpret_cast<const float*>(&lo);
            const float* hip_ = reinterpret_cast<const float*>(&hi);
            #pragma unroll
            for (int t = 0; t < 4; ++t) {
                int d = d0 + t;                       // 0..31 (freq index)
                float invf = __expf(-(float)d * (9.210340371976184f / 32.0f)); // 10000^(-d/32)
                float ang  = (float)sidx * invf;
                float sn, cs;
                __sincosf(ang, &sn, &cs);
                olo[t] = lop[t] * cs - hip_[t] * sn;  // x*cos - x_hi*sin
                ohi[t] = hip_[t] * cs + lop[t] * sn;  // x_hi*cos + x_lo*sin
            }
            *reinterpret_cast<float4*>(&dst[swz(row, d0)])      = make_float4(olo[0], olo[1], olo[2], olo[3]);
            *reinterpret_cast<float4*>(&dst[swz(row, d0 + 32)]) = make_float4(ohi[0], ohi[1], ohi[2], ohi[3]);
        }
    };
    auto stage_v = [&](int kk0) {
        #pragma unroll
        for (int r = 0; r < 4; ++r) {
            int task = tid + r * 256;                 // 1024 float4s
            int row  = task >> 4;
            int d0   = (task & 15) * 4;
            float4 val = *reinterpret_cast<const float4*>(Vbase + (long)(kk0 + row) * (HEADS * DDIM) + d0);
            *reinterpret_cast<float4*>(&v_s[swz(row, d0)]) = val;
        }
    };

    // stage Q' (RoPE applied) once for the block
    stage_rope(Qbase, q0, q_s);

    // lane roles: score phase: keys j = jd + 16*jj ; queries i = iq + 4*ii
    //             PV phase   : d-cols = jd*4+dd    ; queries i = iq + 4*ii
    const int jd = lane & 15;
    const int iq = lane >> 4;
    const int qbase = q0 + wave * 16;
    float* pw = &p_s[wave][0];

    float m[4], l[4], acc[4][4];
    #pragma unroll
    for (int ii = 0; ii < 4; ++ii) {
        m[ii] = NEG; l[ii] = 0.f;
        #pragma unroll
        for (int dd = 0; dd < 4; ++dd) acc[ii][dd] = 0.f;
    }

    for (int c = 0; c < 5; ++c) {
        const int kc0 = q0 - 256 + c * 64;
        if (kc0 < 0) continue;                // chunk origins are multiples of 64: fully invalid
        __syncthreads();                      // previous chunk's compute done
        stage_rope(Kbase, kc0, k_s);
        stage_v(kc0);
        __syncthreads();

        // ---- scores: 4x4 per-lane register tile -------------------------
        float sc[4][4];
        #pragma unroll
        for (int ii = 0; ii < 4; ++ii)
            #pragma unroll
            for (int jj = 0; jj < 4; ++jj) sc[ii][jj] = 0.f;

        #pragma unroll 2
        for (int d0 = 0; d0 < 64; d0 += 4) {
            float4 qv[4], kv[4];
            #pragma unroll
            for (int ii = 0; ii < 4; ++ii)
                qv[ii] = *reinterpret_cast<const float4*>(&q_s[swz(wave * 16 + iq + 4 * ii, d0)]);
            #pragma unroll
            for (int jj = 0; jj < 4; ++jj)
                kv[jj] = *reinterpret_cast<const float4*>(&k_s[swz(jd + 16 * jj, d0)]);
            #pragma unroll
            for (int ii = 0; ii < 4; ++ii)
                #pragma unroll
                for (int jj = 0; jj < 4; ++jj)
                    sc[ii][jj] += qv[ii].x * kv[jj].x + qv[ii].y * kv[jj].y
                                + qv[ii].z * kv[jj].z + qv[ii].w * kv[jj].w;
        }

        // ---- online softmax over the 16 lanes sharing iq ----------------
        float pmat[4][4], rr[4];
        #pragma unroll
        for (int ii = 0; ii < 4; ++ii) {
            const int qi = qbase + iq + 4 * ii;
            float sm[4]; bool ok[4];
            float cmax = NEG;
            #pragma unroll
            for (int jj = 0; jj < 4; ++jj) {
                int kk = kc0 + jd + 16 * jj;
                ok[jj] = (kk <= qi) && (kk + 256 >= qi);
                sm[jj] = ok[jj] ? sc[ii][jj] * SCALE : NEG;
                cmax = fmaxf(cmax, sm[jj]);
            }
            cmax = fmaxf(cmax, __shfl_xor(cmax, 1, 64));
            cmax = fmaxf(cmax, __shfl_xor(cmax, 2, 64));
            cmax = fmaxf(cmax, __shfl_xor(cmax, 4, 64));
            cmax = fmaxf(cmax, __shfl_xor(cmax, 8, 64));
            const float newm = fmaxf(m[ii], cmax);
            const float r = __expf(m[ii] - newm);
            float psum = 0.f;
            #pragma unroll
            for (int jj = 0; jj < 4; ++jj) {
                float p = ok[jj] ? __expf(sm[jj] - newm) : 0.f;
                pmat[ii][jj] = p;
                psum += p;
            }
            psum += __shfl_xor(psum, 1, 64);
            psum += __shfl_xor(psum, 2, 64);
            psum += __shfl_xor(psum, 4, 64);
            psum += __shfl_xor(psum, 8, 64);
            l[ii] = l[ii] * r + psum;
            m[ii] = newm;
            rr[ii] = r;
        }

        // P^T to per-wave LDS: layout [j][i_local], i_local = iq*4+ii packed,
        // column-swizzled by (j&3) to spread write banks.
        #pragma unroll
        for (int jj = 0; jj < 4; ++jj) {
            int j = jd + 16 * jj;
            float4 pj = make_float4(pmat[0][jj], pmat[1][jj], pmat[2][jj], pmat[3][jj]);
            *reinterpret_cast<float4*>(&pw[j * 16 + ((iq * 4) ^ ((j & 3) << 2))]) = pj;
        }

        // ---- PV: lane owns (iq-group, d-group=jd) -----------------------
        #pragma unroll
        for (int ii = 0; ii < 4; ++ii) {
            acc[ii][0] *= rr[ii]; acc[ii][1] *= rr[ii];
            acc[ii][2] *= rr[ii]; acc[ii][3] *= rr[ii];
        }
        #pragma unroll 4
        for (int j = 0; j < 64; ++j) {
            float4 pr = *reinterpret_cast<const float4*>(&pw[j * 16 + ((iq * 4) ^ ((j & 3) << 2))]);
            float4 vr = *reinterpret_cast<const float4*>(&v_s[swz(j, jd * 4)]);
            const float* prp = reinterpret_cast<const float*>(&pr);
            #pragma unroll
            for (int ii = 0; ii < 4; ++ii) {
                float p = prp[ii];
                acc[ii][0] += p * vr.x; acc[ii][1] += p * vr.y;
                acc[ii][2] += p * vr.z; acc[ii][3] += p * vr.w;
            }
        }
    }

    // ---- epilogue: out = acc / l, coalesced float4 stores ---------------
    #pragma unroll
    for (int ii = 0; ii < 4; ++ii) {
        const int qi = qbase + iq + 4 * ii;
        const float inv = 1.0f / l[ii];
        float4 o = make_float4(acc[ii][0] * inv, acc[ii][1] * inv,
                               acc[ii][2] * inv, acc[ii][3] * inv);
        *reinterpret_cast<float4*>(&Obase[(long)qi * (HEADS * DDIM) + jd * 4]) = o;
    }
}

extern "C" void kernel_launch(void* const* d_in, const int* in_sizes, int n_in,
                              void* d_out, int out_size, void* d_ws, size_t ws_size,
                              hipStream_t stream) {
    const float* q = (const float*)d_in[0];
    const float* k = (const float*)d_in[1];
    const float* v = (const float*)d_in[2];
    float* o = (float*)d_out;
    dim3 grid(2 * HEADS * (S_LEN / QT));   // 1024 blocks
    dim3 block(256);
    hipLaunchKernelGGL(fattn_kernel, grid, block, 0, stream, q, k, v, o);
}

// Round 2
// 122.678 us; speedup vs baseline: 1.4952x; 1.4952x over previous
//
#include <hip/hip_runtime.h>

typedef __attribute__((ext_vector_type(4))) float  f32x4;
typedef __attribute__((ext_vector_type(8))) short  short8v;
typedef __attribute__((ext_vector_type(4))) short  short4v;

constexpr int S_LEN = 2048;
constexpr int HEADS = 16;
constexpr int DDIM  = 64;
constexpr int QT    = 64;
constexpr int ROWSZ = HEADS * DDIM;          // 1024 elements per s-step
constexpr float SCALE = 0.125f;              // 64^-0.5
constexpr float NEG   = -1e30f;
constexpr float RLN   = 0.2878231366242557f; // ln(10000)/32
constexpr float RSTEP = 0.74989420933246f;   // 10000^(-1/32)
constexpr long  NELEM = (long)2 * S_LEN * HEADS * DDIM;  // 4194304 per tensor

// LDS rows of 64 bf16 (128B); XOR swizzle spreads 8 consecutive rows over
// 8 distinct 16B slots -> worst case 2-way conflict on b128 reads (free).
__device__ __forceinline__ int swz(int row, int d) { return row * 64 + (d ^ ((row & 7) << 3)); }

// f32 -> bf16 bits, round-to-nearest-even (no NaN care needed here)
__device__ __forceinline__ short f2b(float x) {
    unsigned u = __float_as_uint(x);
    return (short)((u + 0x7FFFu + ((u >> 16) & 1u)) >> 16);
}

// ---------------------------------------------------------------------------
// Prep pass: RoPE(Q), RoPE(K) -> bf16; V -> bf16. 2048 blocks x 256 threads.
// Layout in ws identical to input layout ([b][s][h][d]), bf16 elements.
// ---------------------------------------------------------------------------
__global__ __launch_bounds__(256) void prep_kernel(const float* __restrict__ Q,
                                                   const float* __restrict__ K,
                                                   const float* __restrict__ V,
                                                   short* __restrict__ qw,
                                                   short* __restrict__ kw,
                                                   short* __restrict__ vw) {
    const int tid = blockIdx.x * 256 + threadIdx.x;       // 524288 threads
    // ---- RoPE task: row = tid>>3 over 65536 (b,s,h) rows, d0 = (tid&7)*4
    {
        const int row = tid >> 3;
        const int d0  = (tid & 7) * 4;
        const int s   = (row >> 4) & (S_LEN - 1);         // h is innermost (16)
        const long off = (long)row * DDIM + d0;
        float sn[4], cs[4];
        float invf = __expf(-(float)d0 * RLN);
        #pragma unroll
        for (int t = 0; t < 4; ++t) {
            __sincosf((float)s * invf, &sn[t], &cs[t]);
            invf *= RSTEP;
        }
        {
            float4 lo = *reinterpret_cast<const float4*>(Q + off);
            float4 hi = *reinterpret_cast<const float4*>(Q + off + 32);
            const float* lp = reinterpret_cast<const float*>(&lo);
            const float* hp = reinterpret_cast<const float*>(&hi);
            short4v olo, ohi;
            #pragma unroll
            for (int t = 0; t < 4; ++t) {
                olo[t] = f2b(lp[t] * cs[t] - hp[t] * sn[t]);
                ohi[t] = f2b(hp[t] * cs[t] + lp[t] * sn[t]);
            }
            *reinterpret_cast<short4v*>(qw + off)      = olo;
            *reinterpret_cast<short4v*>(qw + off + 32) = ohi;
        }
        {
            float4 lo = *reinterpret_cast<const float4*>(K + off);
            float4 hi = *reinterpret_cast<const float4*>(K + off + 32);
            const float* lp = reinterpret_cast<const float*>(&lo);
            const float* hp = reinterpret_cast<const float*>(&hi);
            short4v olo, ohi;
            #pragma unroll
            for (int t = 0; t < 4; ++t) {
                olo[t] = f2b(lp[t] * cs[t] - hp[t] * sn[t]);
                ohi[t] = f2b(hp[t] * cs[t] + lp[t] * sn[t]);
            }
            *reinterpret_cast<short4v*>(kw + off)      = olo;
            *reinterpret_cast<short4v*>(kw + off + 32) = ohi;
        }
    }
    // ---- V convert: 1048576 float4 chunks, 2 per thread
    #pragma unroll
    for (int k2 = 0; k2 < 2; ++k2) {
        const long c = (long)tid + (long)k2 * 524288;
        float4 v = *reinterpret_cast<const float4*>(V + c * 4);
        short4v o;
        o[0] = f2b(v.x); o[1] = f2b(v.y); o[2] = f2b(v.z); o[3] = f2b(v.w);
        *reinterpret_cast<short4v*>(vw + c * 4) = o;
    }
}

// ---------------------------------------------------------------------------
// Flash attention, 64 queries/block, MFMA 16x16x32 bf16.
// PRE=true: inputs are prepped bf16 (RoPE done). PRE=false: f32 + in-kernel RoPE.
// ---------------------------------------------------------------------------
template <bool PRE>
__global__ __launch_bounds__(256, 3) void fattn_mfma(const void* __restrict__ Qp,
                                                     const void* __restrict__ Kp,
                                                     const void* __restrict__ Vp,
                                                     float* __restrict__ O) {
    __shared__ __align__(16) short q_s[64 * 64];
    __shared__ __align__(16) short k_s[64 * 64];
    __shared__ __align__(16) short v_t[64 * 64];        // transposed: row=d, col=j
    __shared__ __align__(16) short p_s[4][16 * 64];     // per-wave P: row=i_loc, col=j

    const int tid  = threadIdx.x;
    const int wave = tid >> 6;
    const int lane = tid & 63;
    const int col  = lane & 15;     // MFMA row/col lane index
    const int grp  = lane >> 4;     // 0..3

    const int ntile = S_LEN / QT;   // 32
    const int qt = blockIdx.x % ntile;
    const int bh = blockIdx.x / ntile;
    const int b  = bh / HEADS, h = bh % HEADS;
    const int q0 = qt * QT;
    const long bhoff = ((long)b * S_LEN * HEADS + h) * DDIM;

    const float* Qf = (const float*)Qp + bhoff;
    const float* Kf = (const float*)Kp + bhoff;
    const float* Vf = (const float*)Vp + bhoff;
    const short* Qb = (const short*)Qp + bhoff;
    const short* Kb = (const short*)Kp + bhoff;
    const short* Vb = (const short*)Vp + bhoff;

    // ---- staging: Q'/K' rows (RoPE already applied if PRE) into swizzled LDS
    auto stage_qk = [&](const float* fbase, const short* bbase, int row0, short* dst) {
        #pragma unroll
        for (int r = 0; r < 2; ++r) {
            const int task = tid + r * 256;               // 512 tasks: 64 rows x 8 dgroups
            const int row  = task >> 3;
            const int d0   = (task & 7) * 4;
            const int sidx = row0 + row;
            const long off = (long)sidx * ROWSZ + d0;
            short4v olo, ohi;
            if constexpr (PRE) {
                olo = *reinterpret_cast<const short4v*>(bbase + off);
                ohi = *reinterpret_cast<const short4v*>(bbase + off + 32);
            } else {
                float4 lo = *reinterpret_cast<const float4*>(fbase + off);
                float4 hi = *reinterpret_cast<const float4*>(fbase + off + 32);
                const float* lp = reinterpret_cast<const float*>(&lo);
                const float* hp = reinterpret_cast<const float*>(&hi);
                float invf = __expf(-(float)d0 * RLN);
                #pragma unroll
                for (int t = 0; t < 4; ++t) {
                    float sn, cs;
                    __sincosf((float)sidx * invf, &sn, &cs);
                    olo[t] = f2b(lp[t] * cs - hp[t] * sn);
                    ohi[t] = f2b(hp[t] * cs + lp[t] * sn);
                    invf *= RSTEP;
                }
            }
            *reinterpret_cast<short4v*>(&dst[swz(row, d0)])      = olo;
            *reinterpret_cast<short4v*>(&dst[swz(row, d0 + 32)]) = ohi;
        }
    };

    // ---- staging: V transposed into v_t (row=d, col=j), paired b32 writes
    auto stage_v = [&](int kk0) {
        #pragma unroll
        for (int r = 0; r < 2; ++r) {
            const int task = tid + r * 256;               // 512 tasks: 32 row-pairs x 16 dgroups
            const int jp   = (task >> 4) * 2;             // 0,2,..,62
            const int d0   = (task & 15) * 4;
            short a[4], c[4];
            if constexpr (PRE) {
                short4v va = *reinterpret_cast<const short4v*>(Vb + (long)(kk0 + jp) * ROWSZ + d0);
                short4v vb = *reinterpret_cast<const short4v*>(Vb + (long)(kk0 + jp + 1) * ROWSZ + d0);
                #pragma unroll
                for (int t = 0; t < 4; ++t) { a[t] = va[t]; c[t] = vb[t]; }
            } else {
                float4 va = *reinterpret_cast<const float4*>(Vf + (long)(kk0 + jp) * ROWSZ + d0);
                float4 vb = *reinterpret_cast<const float4*>(Vf + (long)(kk0 + jp + 1) * ROWSZ + d0);
                a[0] = f2b(va.x); a[1] = f2b(va.y); a[2] = f2b(va.z); a[3] = f2b(va.w);
                c[0] = f2b(vb.x); c[1] = f2b(vb.y); c[2] = f2b(vb.z); c[3] = f2b(vb.w);
            }
            #pragma unroll
            for (int t = 0; t < 4; ++t) {
                int packed = (int)(unsigned short)a[t] | ((int)(unsigned short)c[t] << 16);
                *reinterpret_cast<int*>(&v_t[swz(d0 + t, jp)]) = packed;
            }
        }
    };

    // ---- stage Q once, load per-wave A-fragments
    stage_qk(Qf, Qb, q0, q_s);
    __syncthreads();
    const short8v qa0 = *reinterpret_cast<const short8v*>(&q_s[swz(wave * 16 + col, grp * 8)]);
    const short8v qa1 = *reinterpret_cast<const short8v*>(&q_s[swz(wave * 16 + col, 32 + grp * 8)]);

    f32x4 acc[4];
    float m[4], l[4];
    #pragma unroll
    for (int r = 0; r < 4; ++r) {
        m[r] = NEG; l[r] = 0.f;
        acc[0][r] = 0.f; acc[1][r] = 0.f; acc[2][r] = 0.f; acc[3][r] = 0.f;
    }
    const int qb = q0 + wave * 16;

    for (int c = 0; c < 5; ++c) {
        const int kc0 = q0 - 256 + c * 64;
        if (kc0 < 0) continue;                    // uniform across block
        __syncthreads();
        stage_qk(Kf, Kb, kc0, k_s);
        stage_v(kc0);
        __syncthreads();

        // ---- QK^T: 4 j-tiles x 2 k-halves
        f32x4 sv[4];
        #pragma unroll
        for (int jt = 0; jt < 4; ++jt) {
            short8v kb0 = *reinterpret_cast<const short8v*>(&k_s[swz(jt * 16 + col, grp * 8)]);
            short8v kb1 = *reinterpret_cast<const short8v*>(&k_s[swz(jt * 16 + col, 32 + grp * 8)]);
            f32x4 z = {0.f, 0.f, 0.f, 0.f};
            z      = __builtin_amdgcn_mfma_f32_16x16x32_bf16(qa0, kb0, z, 0, 0, 0);
            sv[jt] = __builtin_amdgcn_mfma_f32_16x16x32_bf16(qa1, kb1, z, 0, 0, 0);
        }

        // ---- mask + scale + row-max (rows i = qb + grp*4 + r, col j)
        float mx[4] = {NEG, NEG, NEG, NEG};
        #pragma unroll
        for (int jt = 0; jt < 4; ++jt) {
            const int j = kc0 + jt * 16 + col;
            #pragma unroll
            for (int r = 0; r < 4; ++r) {
                const int i = qb + grp * 4 + r;
                const bool ok = (j <= i) && (j + 256 >= i);
                float s = ok ? sv[jt][r] * SCALE : NEG;
                sv[jt][r] = s;
                mx[r] = fmaxf(mx[r], s);
            }
        }
        #pragma unroll
        for (int r = 0; r < 4; ++r) {
            float v = mx[r];
            v = fmaxf(v, __shfl_xor(v, 1, 64));
            v = fmaxf(v, __shfl_xor(v, 2, 64));
            v = fmaxf(v, __shfl_xor(v, 4, 64));
            v = fmaxf(v, __shfl_xor(v, 8, 64));
            mx[r] = v;
        }
        float rr[4], ps[4];
        #pragma unroll
        for (int r = 0; r < 4; ++r) {
            const float nm = fmaxf(m[r], mx[r]);
            rr[r] = __expf(m[r] - nm);
            m[r] = nm;
            ps[r] = 0.f;
        }
        // ---- P = exp(s-m); bf16 into per-wave LDS [i_loc][j]
        // (masked s = NEG -> p underflows to exactly 0; every row has a valid
        //  key in its first processed chunk, so m is real before any all-masked chunk)
        #pragma unroll
        for (int jt = 0; jt < 4; ++jt) {
            #pragma unroll
            for (int r = 0; r < 4; ++r) {
                float p = __expf(sv[jt][r] - m[r]);
                ps[r] += p;
                const int iloc = grp * 4 + r;
                p_s[wave][swz(iloc, jt * 16 + col)] = f2b(p);
            }
        }
        #pragma unroll
        for (int r = 0; r < 4; ++r) {
            float v = ps[r];
            v += __shfl_xor(v, 1, 64);
            v += __shfl_xor(v, 2, 64);
            v += __shfl_xor(v, 4, 64);
            v += __shfl_xor(v, 8, 64);
            l[r] = l[r] * rr[r] + v;
            acc[0][r] *= rr[r]; acc[1][r] *= rr[r];
            acc[2][r] *= rr[r]; acc[3][r] *= rr[r];
        }

        // ---- PV: A = P (rows=i), B = V^T-staged (k=j both sides, same lane map)
        short8v pa0 = *reinterpret_cast<const short8v*>(&p_s[wave][swz(col, grp * 8)]);
        short8v pa1 = *reinterpret_cast<const short8v*>(&p_s[wave][swz(col, 32 + grp * 8)]);
        #pragma unroll
        for (int dt = 0; dt < 4; ++dt) {
            short8v vb0 = *reinterpret_cast<const short8v*>(&v_t[swz(dt * 16 + col, grp * 8)]);
            short8v vb1 = *reinterpret_cast<const short8v*>(&v_t[swz(dt * 16 + col, 32 + grp * 8)]);
            acc[dt] = __builtin_amdgcn_mfma_f32_16x16x32_bf16(pa0, vb0, acc[dt], 0, 0, 0);
            acc[dt] = __builtin_amdgcn_mfma_f32_16x16x32_bf16(pa1, vb1, acc[dt], 0, 0, 0);
        }
    }

    // ---- epilogue: O[i][d] = acc/l ; lanes 0..15 cover 16 consecutive d (coalesced 64B)
    float* Ob = O + bhoff;
    #pragma unroll
    for (int r = 0; r < 4; ++r) {
        const float inv = 1.0f / l[r];
        const int i = qb + grp * 4 + r;
        #pragma unroll
        for (int dt = 0; dt < 4; ++dt) {
            Ob[(long)i * ROWSZ + dt * 16 + col] = acc[dt][r] * inv;
        }
    }
}

extern "C" void kernel_launch(void* const* d_in, const int* in_sizes, int n_in,
                              void* d_out, int out_size, void* d_ws, size_t ws_size,
                              hipStream_t stream) {
    const float* q = (const float*)d_in[0];
    const float* k = (const float*)d_in[1];
    const float* v = (const float*)d_in[2];
    float* o = (float*)d_out;
    const size_t need = 3ull * NELEM * sizeof(short);   // 24 MB
    dim3 block(256);
    if (d_ws && ws_size >= need) {
        short* qw = (short*)d_ws;
        short* kw = qw + NELEM;
        short* vw = kw + NELEM;
        prep_kernel<<<dim3(2048), block, 0, stream>>>(q, k, v, qw, kw, vw);
        fattn_mfma<true><<<dim3(2 * HEADS * (S_LEN / QT)), block, 0, stream>>>(qw, kw, vw, o);
    } else {
        fattn_mfma<false><<<dim3(2 * HEADS * (S_LEN / QT)), block, 0, stream>>>(q, k, v, o);
    }
}